// Round 10
// baseline (5390.523 us; speedup 1.0000x reference)
//
#include <hip/hip_runtime.h>
#include <hip/hip_bf16.h>

#define Bb 32
#define Tt 512
#define Ii 256
#define Hh 512
#define Oo 128
#define NG 32   // wgs per direction in recurrence

using bf16x8 = __attribute__((ext_vector_type(8))) __bf16;
using f32x4  = __attribute__((ext_vector_type(4))) float;

__device__ __forceinline__ bf16x8 f32x8_to_bf16(const float* p) {
    const float4 u = *reinterpret_cast<const float4*>(p);
    const float4 v = *reinterpret_cast<const float4*>(p + 4);
    bf16x8 r;
    r[0] = (__bf16)u.x; r[1] = (__bf16)u.y; r[2] = (__bf16)u.z; r[3] = (__bf16)u.w;
    r[4] = (__bf16)v.x; r[5] = (__bf16)v.y; r[6] = (__bf16)v.z; r[7] = (__bf16)v.w;
    return r;
}

__device__ __forceinline__ float sigm(float x) { return 1.f / (1.f + __expf(-x)); }
__device__ __forceinline__ float tanh_fast(float x) {
    const float e = __expf(2.f * x);
    return 1.f - 2.f / (e + 1.f);
}
__device__ __forceinline__ unsigned short bfbits(float x) {
    return __builtin_bit_cast(unsigned short, (__bf16)x);
}
__device__ __forceinline__ float us2f(unsigned short u) {
    return __builtin_bit_cast(float, (unsigned)u << 16);
}

// ---------------- setup: zero flags, build initial h (fwd=0, bwd=bh0) -------
__global__ void k_setup(const float* __restrict__ bh0,
                        __bf16* __restrict__ hinit, int* __restrict__ flags) {
    const int tid = blockIdx.x * 256 + threadIdx.x;
    if (tid < 64) flags[tid] = 0;          // 256 B of u8 flags [2][128]
    if (tid < Bb * Hh) {
        hinit[tid] = (__bf16)0.f;
        hinit[Bb * Hh + tid] = (__bf16)bh0[tid & (Hh - 1)];
    }
}

// ---------------- one-time Wh f32 -> bf16, layout [4][512 hcol][512 k] -------
__global__ __launch_bounds__(256) void k_wcvt(
    const float* __restrict__ Wf, const float* __restrict__ Wi,
    const float* __restrict__ Wo, const float* __restrict__ Wc,
    __bf16* __restrict__ Whb)
{
    const int e = (blockIdx.x * 256 + threadIdx.x) * 4;
    const int g = e >> 18;
    const int rem = e & 262143;
    const int hr = rem >> 9;
    const int k  = rem & 511;
    const float* W = (g == 0) ? Wf : (g == 1) ? Wi : (g == 2) ? Wo : Wc;
    const float4 v = *reinterpret_cast<const float4*>(W + (long)hr * 768 + Ii + k);
    uint2 pk;
    pk.x = ((unsigned)bfbits(v.y) << 16) | bfbits(v.x);
    pk.y = ((unsigned)bfbits(v.w) << 16) | bfbits(v.z);
    *reinterpret_cast<uint2*>(Whb + e) = pk;
}

// ---------------- xproj = x @ Wx^T + b  -> [T][4H][B] bf16 -------------------
__global__ __launch_bounds__(256) void k_xproj(
    const float* __restrict__ x,
    const float* __restrict__ Wf, const float* __restrict__ bf_,
    const float* __restrict__ Wi, const float* __restrict__ bi_,
    const float* __restrict__ Wo, const float* __restrict__ bo_,
    const float* __restrict__ Wc, const float* __restrict__ bc_,
    __bf16* __restrict__ xproj)
{
    const int wgM = blockIdx.x;           // 0..255  (64 rows each)
    const int wgN = blockIdx.y;           // 0..15   (128 cols each)
    const int tid = threadIdx.x;
    const int wave = tid >> 6, lane = tid & 63;
    const int mw = wave >> 1, nw = wave & 1;
    const int l15 = lane & 15, lhi = lane >> 4;

    const int gamma = wgN >> 2;
    const float* W    = (gamma == 0) ? Wf : (gamma == 1) ? Wi : (gamma == 2) ? Wo : Wc;
    const float* bptr = (gamma == 0) ? bf_ : (gamma == 1) ? bi_ : (gamma == 2) ? bo_ : bc_;

    f32x4 acc[2][4];
#pragma unroll
    for (int m = 0; m < 2; m++)
#pragma unroll
        for (int n = 0; n < 4; n++) acc[m][n] = f32x4{0.f, 0.f, 0.f, 0.f};

    const int rowbase = wgM * 64 + mw * 32;
    const int colbase = wgN * 128 + nw * 64;

#pragma unroll
    for (int kk = 0; kk < 8; ++kk) {
        const int k0 = kk * 32 + lhi * 8;
        bf16x8 a[2], b[4];
#pragma unroll
        for (int m = 0; m < 2; m++) {
            const int r = rowbase + m * 16 + l15;        // x row = b*T + t
            a[m] = f32x8_to_bf16(x + (long)r * Ii + k0);
        }
#pragma unroll
        for (int n = 0; n < 4; n++) {
            const int g = colbase + n * 16 + l15;
            b[n] = f32x8_to_bf16(W + (long)(g & 511) * 768 + k0);
        }
#pragma unroll
        for (int m = 0; m < 2; m++)
#pragma unroll
            for (int n = 0; n < 4; n++)
                acc[m][n] = __builtin_amdgcn_mfma_f32_16x16x32_bf16(a[m], b[n], acc[m][n], 0, 0, 0);
    }

#pragma unroll
    for (int m = 0; m < 2; m++)
#pragma unroll
        for (int n = 0; n < 4; n++) {
            const int g = colbase + n * 16 + l15;        // gate-col 0..2047
            const float bias = bptr[g & 511];
#pragma unroll
            for (int r = 0; r < 4; r++) {
                const int R = rowbase + m * 16 + lhi * 4 + r;   // = b*T + t
                const int t = R & (Tt - 1), bb = R >> 9;
                xproj[((long)t * 2048 + g) * Bb + bb] = (__bf16)(acc[m][n][r] + bias);
            }
        }
}

// ---- recurrence: 64 wgs (32/dir), barrier-free autonomous waves -------------
// Per wave: A = 16 W-rows from read-only LDS; B = full h loaded straight from
// LLC into registers (32x dwordx4, one vmcnt). Zero per-step barriers.
__global__ __launch_bounds__(256, 1) void k_rec(
    const __bf16* __restrict__ Whb,    // [4][512][512] bf16
    const float* __restrict__ bc0,
    const __bf16* __restrict__ xproj,  // [T][4H][B]
    __bf16* __restrict__ hs,           // [2][T][B][H]
    const __bf16* __restrict__ hinit,  // [2][B][H]
    unsigned char* flags)              // [2 dirs][128 wave-producers] u8
{
    const int dir  = blockIdx.x >> 5;
    const int gsel = blockIdx.x & 31;       // owns h-cols [gsel*16, +16)
    const int tid  = threadIdx.x;
    const int wave = tid >> 6;              // 0..3 : 4 h-cols each
    const int lane = tid & 63;
    const int l15  = lane & 15, lhi = lane >> 4;

    __shared__ __bf16 Wlds[64 * 512];       // 64 KiB, rows j = hc_local*4+gate

    // one-time: copy this wg's weight slice into LDS (swizzled), read-only after
    char* wl = reinterpret_cast<char*>(Wlds);
    for (int c = tid; c < 4096; c += 256) {
        const int row = c >> 6, q = c & 63;
        const int gate = row & 3;
        const int hc   = gsel * 16 + (row >> 4) * 4 + ((row & 15) >> 2);
        const bf16x8 w = *reinterpret_cast<const bf16x8*>(
            Whb + (long)(gate * 512 + hc) * 512 + q * 8);
        *reinterpret_cast<bf16x8*>(wl + row * 1024 + ((q * 16) ^ ((row & 7) << 4))) = w;
    }
    __syncthreads();                         // the only barrier in the kernel

    const int hcol = gsel * 16 + wave * 4 + lhi;
    float cs0 = (dir == 0) ? 0.f : bc0[hcol];   // batch l15
    float cs1 = cs0;                            // batch 16+l15

    __bf16* hsd = hs + (long)dir * Tt * Bb * Hh;
    const unsigned* pollbase = reinterpret_cast<const unsigned*>(flags + dir * 128);
    unsigned char* myflag = flags + dir * 128 + gsel * 4 + wave;

    const char* wbase = wl + (wave * 16 + l15) * 1024;
    const int asw = (l15 & 7) << 4;

    for (int s = 0; s < Tt; ++s) {
        const int t = (dir == 0) ? s : (Tt - 1 - s);

        // xproj prefetch (cached loads, independent of flags)
        unsigned short xr0[4], xr1[4];
#pragma unroll
        for (int g = 0; g < 4; ++g) {
            const __bf16* pf = xproj + ((long)t * 2048 + g * 512 + hcol) * Bb;
            xr0[g] = __builtin_bit_cast(unsigned short, pf[l15]);
            xr1[g] = __builtin_bit_cast(unsigned short, pf[16 + l15]);
        }

        // poll own-dir 128 wave-flags with ONE dword load per iteration
        if (s > 0) {
            const unsigned es = (unsigned)(s & 255);
            for (int p = 0; p < 16384; ++p) {
                const unsigned v = __hip_atomic_load(pollbase + (lane & 31),
                                                     __ATOMIC_RELAXED,
                                                     __HIP_MEMORY_SCOPE_AGENT);
                const bool ok =
                    ((unsigned char)((v & 255) - es) <= 1) &&
                    ((unsigned char)(((v >> 8) & 255) - es) <= 1) &&
                    ((unsigned char)(((v >> 16) & 255) - es) <= 1) &&
                    ((unsigned char)(((v >> 24) & 255) - es) <= 1);
                if (__all(ok)) break;
                __builtin_amdgcn_s_sleep(1);
            }
        }

        // load full h_{t-1} as B-fragments straight from LLC (no LDS staging)
        const __bf16* hp = (s == 0) ? (hinit + (long)dir * Bb * Hh)
                                    : (hsd + (long)((dir == 0) ? (t - 1) : (t + 1)) * Bb * Hh);
        const char* h0p = reinterpret_cast<const char*>(hp) + l15 * 1024 + lhi * 16;
        const char* h1p = h0p + 16 * 1024;
        f32x4 B0[16], B1[16];
#pragma unroll
        for (int kk = 0; kk < 16; ++kk) {
            asm volatile("global_load_dwordx4 %0, %1, off sc0 sc1"
                         : "=&v"(B0[kk]) : "v"(h0p + kk * 64) : "memory");
            asm volatile("global_load_dwordx4 %0, %1, off sc0 sc1"
                         : "=&v"(B1[kk]) : "v"(h1p + kk * 64) : "memory");
        }
        asm volatile("s_waitcnt vmcnt(0)" ::: "memory");
        __builtin_amdgcn_sched_barrier(0);

        // C[j][b] = sum_k W[j][k] * h[b][k]; acc[r] = gate r of this hcol
        f32x4 acc0 = f32x4{0.f, 0.f, 0.f, 0.f};
        f32x4 acc1 = f32x4{0.f, 0.f, 0.f, 0.f};
#pragma unroll
        for (int kk = 0; kk < 16; ++kk) {
            const int kb = kk * 64 + lhi * 16;
            const bf16x8 wv = *reinterpret_cast<const bf16x8*>(wbase + (kb ^ asw));
            acc0 = __builtin_amdgcn_mfma_f32_16x16x32_bf16(
                wv, __builtin_bit_cast(bf16x8, B0[kk]), acc0, 0, 0, 0);
            acc1 = __builtin_amdgcn_mfma_f32_16x16x32_bf16(
                wv, __builtin_bit_cast(bf16x8, B1[kk]), acc1, 0, 0, 0);
        }

        // cell update straight out of the accumulator
        float hv0, hv1;
        {
            const float gf = us2f(xr0[0]) + acc0[0];
            const float gi = us2f(xr0[1]) + acc0[1];
            const float go = us2f(xr0[2]) + acc0[2];
            const float gc = us2f(xr0[3]) + acc0[3];
            cs0 = sigm(gf) * cs0 + sigm(gi) * tanh_fast(gc);
            hv0 = sigm(go) * tanh_fast(cs0);
        }
        {
            const float gf = us2f(xr1[0]) + acc1[0];
            const float gi = us2f(xr1[1]) + acc1[1];
            const float go = us2f(xr1[2]) + acc1[2];
            const float gc = us2f(xr1[3]) + acc1[3];
            cs1 = sigm(gf) * cs1 + sigm(gi) * tanh_fast(gc);
            hv1 = sigm(go) * tanh_fast(cs1);
        }
        const unsigned u0 = bfbits(hv0), u1 = bfbits(hv1);
        char* d0 = reinterpret_cast<char*>(hsd + ((long)t * Bb + l15) * Hh + hcol);
        char* d1 = reinterpret_cast<char*>(hsd + ((long)t * Bb + 16 + l15) * Hh + hcol);
        asm volatile("global_store_short %0, %1, off sc0 sc1" :: "v"(d0), "v"(u0) : "memory");
        asm volatile("global_store_short %0, %1, off sc0 sc1" :: "v"(d1), "v"(u1) : "memory");
        asm volatile("s_waitcnt vmcnt(0)" ::: "memory");   // this wave's h at LLC
        if (lane == 0) {
            const unsigned fv = (unsigned)((s + 1) & 255);
            asm volatile("global_store_byte %0, %1, off sc0 sc1"
                         :: "v"(myflag), "v"(fv) : "memory");
        }
    }
}

// ---------------- out = cat(hf,hb) @ out_w^T + out_b -> [B][T][O] fp32 -------
__global__ __launch_bounds__(256) void k_out(
    const __bf16* __restrict__ hs,
    const float* __restrict__ out_w,
    const float* __restrict__ out_b,
    float* __restrict__ out)
{
    const int wgM = blockIdx.x;            // 0..255 (64 hs-rows each)
    const int tid = threadIdx.x;
    const int wave = tid >> 6, lane = tid & 63;
    const int mw = wave >> 1, nw = wave & 1;
    const int l15 = lane & 15, lhi = lane >> 4;

    f32x4 acc[2][4];
#pragma unroll
    for (int m = 0; m < 2; m++)
#pragma unroll
        for (int n = 0; n < 4; n++) acc[m][n] = f32x4{0.f, 0.f, 0.f, 0.f};

    const int rowbase = wgM * 64 + mw * 32;   // hs row = t*B + b
    const int colbase = nw * 64;

#pragma unroll 4
    for (int kk = 0; kk < 32; ++kk) {
        const int k0 = kk * 32 + lhi * 8;     // 0..1023
        const int d = k0 >> 9, hk = k0 & 511;
        bf16x8 a[2], b[4];
#pragma unroll
        for (int m = 0; m < 2; m++) {
            const int R = rowbase + m * 16 + l15;
            a[m] = *reinterpret_cast<const bf16x8*>(hs + ((long)d * 16384 + R) * 512 + hk);
        }
#pragma unroll
        for (int n = 0; n < 4; n++) {
            const int o = colbase + n * 16 + l15;
            b[n] = f32x8_to_bf16(out_w + (long)o * 1024 + k0);
        }
#pragma unroll
        for (int m = 0; m < 2; m++)
#pragma unroll
            for (int n = 0; n < 4; n++)
                acc[m][n] = __builtin_amdgcn_mfma_f32_16x16x32_bf16(a[m], b[n], acc[m][n], 0, 0, 0);
    }

#pragma unroll
    for (int m = 0; m < 2; m++)
#pragma unroll
        for (int n = 0; n < 4; n++) {
            const int o = colbase + n * 16 + l15;
            const float bias = out_b[o];
#pragma unroll
            for (int r = 0; r < 4; r++) {
                const int R = rowbase + m * 16 + lhi * 4 + r;   // t*32 + b
                const int tt = R >> 5, bb = R & 31;
                out[((long)bb * Tt + tt) * Oo + o] = acc[m][n][r] + bias;
            }
        }
}

// ---------------- launcher ---------------------------------------------------
extern "C" void kernel_launch(void* const* d_in, const int* in_sizes, int n_in,
                              void* d_out, int out_size, void* d_ws, size_t ws_size,
                              hipStream_t stream) {
    (void)in_sizes; (void)n_in; (void)out_size; (void)ws_size;
    const float* x    = (const float*)d_in[0];
    const float* Wf_w = (const float*)d_in[1];
    const float* Wf_b = (const float*)d_in[2];
    const float* Wi_w = (const float*)d_in[3];
    const float* Wi_b = (const float*)d_in[4];
    const float* Wo_w = (const float*)d_in[5];
    const float* Wo_b = (const float*)d_in[6];
    const float* Wc_w = (const float*)d_in[7];
    const float* Wc_b = (const float*)d_in[8];
    const float* out_w = (const float*)d_in[9];
    const float* out_b = (const float*)d_in[10];
    const float* bh0  = (const float*)d_in[11];
    const float* bc0  = (const float*)d_in[12];

    char* ws = (char*)d_ws;
    __bf16* xproj = (__bf16*)(ws);                       // 67108864 B  [T][4H][B]
    __bf16* hs    = (__bf16*)(ws + 67108864);            // 33554432 B
    __bf16* hinit = (__bf16*)(ws + 100663296);           // 65536 B
    __bf16* Whb   = (__bf16*)(ws + 100728832);           // 2097152 B
    unsigned char* flags = (unsigned char*)(ws + 102825984);  // 256 B

    k_setup<<<64, 256, 0, stream>>>(bh0, hinit, (int*)flags);
    k_wcvt<<<1024, 256, 0, stream>>>(Wf_w, Wi_w, Wo_w, Wc_w, Whb);
    dim3 g1(256, 16);
    k_xproj<<<g1, 256, 0, stream>>>(x, Wf_w, Wf_b, Wi_w, Wi_b, Wo_w, Wo_b, Wc_w, Wc_b, xproj);
    k_rec<<<2 * NG, 256, 0, stream>>>(Whb, bc0, xproj, hs, hinit, flags);
    k_out<<<256, 256, 0, stream>>>(hs, out_w, out_b, (float*)d_out);
}